// Round 1
// baseline (267.357 us; speedup 1.0000x reference)
//
#include <hip/hip_runtime.h>

#define D_NODE 32
#define D_EDGE 16
#define D_OUT  32
#define D_HID  160
#define EPB    64
#define NEDGE  1600000
#define NTILES (NEDGE / EPB)
#define A1S    104   // bf16 elems/row: 80 data + 16 zeros + 8 pad (13 x 16B slots, odd -> conflict-free)
#define HTS    168   // 160 + 8 pad (21 slots, odd)

typedef float  f32x4  __attribute__((ext_vector_type(4)));
typedef short  short8 __attribute__((ext_vector_type(8)));

static __device__ __forceinline__ ushort f2bf(float f) {
  uint u = __builtin_bit_cast(uint, f);
  return (ushort)((u + 0x7FFFu + ((u >> 16) & 1u)) >> 16);   // RNE
}

__global__ __launch_bounds__(256) void edge_mlp(
    const float* __restrict__ nodes,
    const float* __restrict__ edges,
    const int*   __restrict__ senders,
    const int*   __restrict__ receivers,
    const float* __restrict__ W1,
    const float* __restrict__ b1,
    const float* __restrict__ W2,
    const float* __restrict__ b2,
    float* __restrict__ out)
{
  __shared__ ushort A1[EPB * A1S];     // feats tile, bf16, K padded to 96(+8)
  __shared__ ushort Ht[EPB * HTS];     // hidden tile, bf16
  __shared__ ushort W2p[10 * 512];     // W2 in B-frag order: (kt*2+nt)*512 + lane*8 + j

  const int tid  = threadIdx.x;
  const int lane = tid & 63;
  const int wave = tid >> 6;
  const int wm   = wave >> 1;   // layer-1 edge half (0..1)
  const int wn   = wave & 1;    // layer-1 hid half  (0..1)
  const int g    = lane >> 4;   // 0..3
  const int c    = lane & 15;

  // ---- once per block: W1 B-fragments into registers (15 frags = 60 VGPR) ----
  short8 w1f[15];
#pragma unroll
  for (int kt = 0; kt < 3; ++kt) {
#pragma unroll
    for (int i = 0; i < 5; ++i) {
      short8 f;
      const int n = (wn * 5 + i) * 16 + c;
#pragma unroll
      for (int j = 0; j < 8; ++j) {
        const int k = kt * 32 + g * 8 + j;
        f[j] = (k < 80) ? (short)f2bf(W1[k * D_HID + n]) : (short)0;
      }
      w1f[kt * 5 + i] = f;
    }
  }

  // ---- once per block: W2 packed into LDS in B-frag order ----
  for (int idx = tid; idx < 5120; idx += 256) {
    const int tl = idx >> 9;
    const int l  = (idx >> 3) & 63;
    const int j  = idx & 7;
    const int k  = (tl >> 1) * 32 + ((l >> 4) & 3) * 8 + j;
    const int n  = (tl & 1) * 16 + (l & 15);
    W2p[idx] = f2bf(W2[k * D_OUT + n]);
  }

  // zero-pad A1 cols 80..95 once (cols 96..103 are never read)
  *(uint2*)&A1[(tid >> 2) * A1S + 80 + (tid & 3) * 4] = make_uint2(0u, 0u);

  float b1r[5];
#pragma unroll
  for (int i = 0; i < 5; ++i) b1r[i] = b1[(wn * 5 + i) * 16 + c];
  const float b2r0 = b2[c];
  const float b2r1 = b2[16 + c];

  const int el = tid >> 2;   // staging: edge-local 0..63
  const int p  = tid & 3;    // staging: part

  __syncthreads();

  for (long tile = blockIdx.x; tile < NTILES; tile += gridDim.x) {
    const long e0 = tile * EPB;

    // ---- stage feats: [sender(32) | receiver(32) | edge(16) | 0(16)] as bf16 ----
    {
      const long e   = e0 + el;
      const int  nid = (p < 2) ? senders[e] : receivers[e];
      const float* src = nodes + (size_t)nid * D_NODE + (p & 1) * 16;
      const float4 v0 = *(const float4*)(src + 0);
      const float4 v1 = *(const float4*)(src + 4);
      const float4 v2 = *(const float4*)(src + 8);
      const float4 v3 = *(const float4*)(src + 12);
      short8 lo, hi;
      lo[0] = (short)f2bf(v0.x); lo[1] = (short)f2bf(v0.y);
      lo[2] = (short)f2bf(v0.z); lo[3] = (short)f2bf(v0.w);
      lo[4] = (short)f2bf(v1.x); lo[5] = (short)f2bf(v1.y);
      lo[6] = (short)f2bf(v1.z); lo[7] = (short)f2bf(v1.w);
      hi[0] = (short)f2bf(v2.x); hi[1] = (short)f2bf(v2.y);
      hi[2] = (short)f2bf(v2.z); hi[3] = (short)f2bf(v2.w);
      hi[4] = (short)f2bf(v3.x); hi[5] = (short)f2bf(v3.y);
      hi[6] = (short)f2bf(v3.z); hi[7] = (short)f2bf(v3.w);
      *(short8*)&A1[el * A1S + p * 16]     = lo;
      *(short8*)&A1[el * A1S + p * 16 + 8] = hi;

      const float4 ev = *(const float4*)(edges + (size_t)e * D_EDGE + p * 4);
      uint2 ep;
      ep.x = (uint)f2bf(ev.x) | ((uint)f2bf(ev.y) << 16);
      ep.y = (uint)f2bf(ev.z) | ((uint)f2bf(ev.w) << 16);
      *(uint2*)&A1[el * A1S + 64 + p * 4] = ep;
    }
    __syncthreads();

    // ---- layer 1: [64x96] @ [96x160] ; wave (wm,wn) does 2 M-tiles x 5 N-tiles ----
    f32x4 acc[2][5];
#pragma unroll
    for (int mt = 0; mt < 2; ++mt)
#pragma unroll
      for (int i = 0; i < 5; ++i) acc[mt][i] = (f32x4){0.f, 0.f, 0.f, 0.f};

#pragma unroll
    for (int kt = 0; kt < 3; ++kt) {
      const short8 a0 = *(const short8*)&A1[(wm * 32 + c) * A1S + kt * 32 + g * 8];
      const short8 a1 = *(const short8*)&A1[(wm * 32 + 16 + c) * A1S + kt * 32 + g * 8];
#pragma unroll
      for (int i = 0; i < 5; ++i) {
        acc[0][i] = __builtin_amdgcn_mfma_f32_16x16x32_bf16(a0, w1f[kt * 5 + i], acc[0][i], 0, 0, 0);
        acc[1][i] = __builtin_amdgcn_mfma_f32_16x16x32_bf16(a1, w1f[kt * 5 + i], acc[1][i], 0, 0, 0);
      }
    }

    // bias + sigmoid -> Ht (bf16). C/D: col=lane&15, row=4*(lane>>4)+r
#pragma unroll
    for (int mt = 0; mt < 2; ++mt) {
#pragma unroll
      for (int i = 0; i < 5; ++i) {
        const int col  = (wn * 5 + i) * 16 + c;
        const int rowb = wm * 32 + mt * 16 + g * 4;
#pragma unroll
        for (int r = 0; r < 4; ++r) {
          const float x = acc[mt][i][r] + b1r[i];
          const float s = 1.0f / (1.0f + __expf(-x));
          Ht[(rowb + r) * HTS + col] = f2bf(s);
        }
      }
    }
    __syncthreads();

    // ---- layer 2: [64x160] @ [160x32] ; wave handles 16 edges x 32 outs ----
    f32x4 o0 = (f32x4){0.f, 0.f, 0.f, 0.f};
    f32x4 o1 = (f32x4){0.f, 0.f, 0.f, 0.f};
#pragma unroll
    for (int kt = 0; kt < 5; ++kt) {
      const short8 af  = *(const short8*)&Ht[(wave * 16 + c) * HTS + kt * 32 + g * 8];
      const short8 bb0 = *(const short8*)&W2p[(kt * 2 + 0) * 512 + lane * 8];
      const short8 bb1 = *(const short8*)&W2p[(kt * 2 + 1) * 512 + lane * 8];
      o0 = __builtin_amdgcn_mfma_f32_16x16x32_bf16(af, bb0, o0, 0, 0, 0);
      o1 = __builtin_amdgcn_mfma_f32_16x16x32_bf16(af, bb1, o1, 0, 0, 0);
    }
    float* dst = out + (size_t)(e0 + wave * 16) * D_OUT;
#pragma unroll
    for (int r = 0; r < 4; ++r) {
      dst[(g * 4 + r) * D_OUT + c]      = o0[r] + b2r0;
      dst[(g * 4 + r) * D_OUT + 16 + c] = o1[r] + b2r1;
    }
  }
}

extern "C" void kernel_launch(void* const* d_in, const int* in_sizes, int n_in,
                              void* d_out, int out_size, void* d_ws, size_t ws_size,
                              hipStream_t stream) {
  const float* nodes     = (const float*)d_in[0];
  const float* edges     = (const float*)d_in[1];
  const int*   senders   = (const int*)d_in[2];
  const int*   receivers = (const int*)d_in[3];
  const float* W1        = (const float*)d_in[4];
  const float* b1        = (const float*)d_in[5];
  const float* W2        = (const float*)d_in[6];
  const float* b2        = (const float*)d_in[7];
  float* out = (float*)d_out;

  edge_mlp<<<1536, 256, 0, stream>>>(nodes, edges, senders, receivers,
                                     W1, b1, W2, b2, out);
}

// Round 2
// 254.284 us; speedup vs baseline: 1.0514x; 1.0514x over previous
//
#include <hip/hip_runtime.h>

#define NEDGE   1600000
#define NPT     (NEDGE / 16)     // 100000 pair-tiles (16 edges each)
#define GRID    2500
#define PSTRIDE (GRID * 2)       // 5000 pairs in flight
#define NIT     (NPT / PSTRIDE)  // 20 — exact, no tail
#define HTS     168              // Ht row stride (bf16 elems): 21x16B slots, odd -> conflict-free

typedef float f32x4  __attribute__((ext_vector_type(4)));
typedef short short8 __attribute__((ext_vector_type(8)));

static __device__ __forceinline__ ushort f2bf(float f) {
  uint u = __builtin_bit_cast(uint, f);
  return (ushort)((u + 0x7FFFu + ((u >> 16) & 1u)) >> 16);   // RNE (host-side-ish init only)
}
static __device__ __forceinline__ uint cvt_pk(float lo, float hi) {
  uint r; asm("v_cvt_pk_bf16_f32 %0, %1, %2" : "=v"(r) : "v"(lo), "v"(hi)); return r;
}
static __device__ __forceinline__ float vexp2(float x) {
  float r; asm("v_exp_f32 %0, %1" : "=v"(r) : "v"(x)); return r;
}
static __device__ __forceinline__ float vrcp(float x) {
  float r; asm("v_rcp_f32 %0, %1" : "=v"(r) : "v"(x)); return r;
}
static __device__ __forceinline__ float sigmoidf(float x) {
  // 1/(1+exp(-x)) = rcp(1 + exp2(-x*log2e)); approx ops, fine for bf16-class tolerance
  return vrcp(1.0f + vexp2(x * -1.44269504088896f));
}
static __device__ __forceinline__ short8 pack8(float4 a, float4 b) {
  uint4 u;
  u.x = cvt_pk(a.x, a.y); u.y = cvt_pk(a.z, a.w);
  u.z = cvt_pk(b.x, b.y); u.w = cvt_pk(b.z, b.w);
  return __builtin_bit_cast(short8, u);
}

__global__ __launch_bounds__(256) void edge_mlp(
    const float* __restrict__ nodes, const float* __restrict__ edges,
    const int* __restrict__ senders, const int* __restrict__ receivers,
    const float* __restrict__ W1, const float* __restrict__ b1,
    const float* __restrict__ W2, const float* __restrict__ b2,
    float* __restrict__ out)
{
  // Ht[pair][dbuf][16 edges][168]: the ONLY shared state. 21 KB total.
  __shared__ ushort Ht[2][2][16 * HTS];

  const int tid  = threadIdx.x;
  const int lane = tid & 63;
  const int wave = tid >> 6;
  const int pr   = wave >> 1;   // pair id (independent 16-edge pipeline)
  const int wh   = wave & 1;    // hid half (layer1) / dout half (layer2)
  const int g    = lane >> 4;   // 0..3
  const int c    = lane & 15;

  // ---- W1^T A-fragments in regs: 5 hid-mtiles x 3 ktiles (K padded 80->96;
  //      row k==80 carries b1 so bias rides the MFMA for free) ----
  short8 w1f[5][3];
#pragma unroll
  for (int mt = 0; mt < 5; ++mt) {
#pragma unroll
    for (int kt = 0; kt < 3; ++kt) {
      const int hid = wh * 80 + mt * 16 + c;
      uint d[4];
#pragma unroll
      for (int dw = 0; dw < 4; ++dw) {
        const int k0 = kt * 32 + g * 8 + dw * 2;
        const int k1 = k0 + 1;
        ushort lo = (k0 < 80) ? f2bf(W1[k0 * 160 + hid]) : (k0 == 80 ? f2bf(b1[hid]) : (ushort)0);
        ushort hi = (k1 < 80) ? f2bf(W1[k1 * 160 + hid]) : (k1 == 80 ? f2bf(b1[hid]) : (ushort)0);
        d[dw] = (uint)lo | ((uint)hi << 16);
      }
      uint4 u = make_uint4(d[0], d[1], d[2], d[3]);
      w1f[mt][kt] = __builtin_bit_cast(short8, u);
    }
  }

  // ---- W2 B-fragments in regs: 5 ktiles for this wave's dout half ----
  short8 w2f[5];
#pragma unroll
  for (int kt = 0; kt < 5; ++kt) {
    uint d[4];
#pragma unroll
    for (int dw = 0; dw < 4; ++dw) {
      const int k = kt * 32 + g * 8 + dw * 2;
      ushort lo = f2bf(W2[k * 32 + wh * 16 + c]);
      ushort hi = f2bf(W2[(k + 1) * 32 + wh * 16 + c]);
      d[dw] = (uint)lo | ((uint)hi << 16);
    }
    uint4 u = make_uint4(d[0], d[1], d[2], d[3]);
    w2f[kt] = __builtin_bit_cast(short8, u);
  }
  const float b2r = b2[wh * 16 + c];
  const uint  cE0 = (g == 2) ? 0x3F80u : 0u;   // bf16(1.0) ones-column at k==80

  // ---- prologue: load tile 0 feats + tile 1 indices ----
  long pt = (long)blockIdx.x * 2 + pr;
  {
  }
  const int e = (int)pt * 16 + c;
  const int si = senders[e], ri = receivers[e];
  const float* sp = nodes + (size_t)si * 32 + g * 8;
  float4 sn0 = *(const float4*)sp, sn1 = *(const float4*)(sp + 4);
  const float* rp = nodes + (size_t)ri * 32 + g * 8;
  float4 rn0 = *(const float4*)rp, rn1 = *(const float4*)(rp + 4);
  const float* ep = edges + (size_t)e * 16 + (g & 1) * 8;
  float4 ee0 = *(const float4*)ep, ee1 = *(const float4*)(ep + 4);

  long ptB = pt + PSTRIDE; if (ptB >= NPT) ptB = pt;   // next tile (clamped; junk iters harmless)
  int  eB  = (int)ptB * 16 + c;
  int  siB = senders[eB], riB = receivers[eB];

  int buf = 0;

  for (int it = 0; it < NIT; ++it) {
    // 1) current feats -> bf16 B-fragments (waits the in-flight gather)
    short8 bfS = pack8(sn0, sn1);
    short8 bfR = pack8(rn0, rn1);
    uint4 ue;
    ue.x = (g < 2) ? cvt_pk(ee0.x, ee0.y) : cE0;
    ue.y = (g < 2) ? cvt_pk(ee0.z, ee0.w) : 0u;
    ue.z = (g < 2) ? cvt_pk(ee1.x, ee1.y) : 0u;
    ue.w = (g < 2) ? cvt_pk(ee1.z, ee1.w) : 0u;
    short8 bfE = __builtin_bit_cast(short8, ue);

    // 2) layer 1 (swapped): acc[mt] = W1^T(mt) x feats^T  -> D[hid][edge]
    f32x4 acc[5];
#pragma unroll
    for (int mt = 0; mt < 5; ++mt) acc[mt] = (f32x4){0.f, 0.f, 0.f, 0.f};
#pragma unroll
    for (int mt = 0; mt < 5; ++mt)
      acc[mt] = __builtin_amdgcn_mfma_f32_16x16x32_bf16(w1f[mt][0], bfS, acc[mt], 0, 0, 0);
#pragma unroll
    for (int mt = 0; mt < 5; ++mt)
      acc[mt] = __builtin_amdgcn_mfma_f32_16x16x32_bf16(w1f[mt][1], bfR, acc[mt], 0, 0, 0);
#pragma unroll
    for (int mt = 0; mt < 5; ++mt)
      acc[mt] = __builtin_amdgcn_mfma_f32_16x16x32_bf16(w1f[mt][2], bfE, acc[mt], 0, 0, 0);

    // 3) issue next tile's gather (lands during phases 4-6 + next barrier)
    {
      const float* spB = nodes + (size_t)siB * 32 + g * 8;
      sn0 = *(const float4*)spB; sn1 = *(const float4*)(spB + 4);
      const float* rpB = nodes + (size_t)riB * 32 + g * 8;
      rn0 = *(const float4*)rpB; rn1 = *(const float4*)(rpB + 4);
      const float* epB = edges + (size_t)eB * 16 + (g & 1) * 8;
      ee0 = *(const float4*)epB; ee1 = *(const float4*)(epB + 4);
      long pt2 = pt + 2 * PSTRIDE; if (pt2 >= NPT) pt2 = pt;
      const int e2 = (int)pt2 * 16 + c;
      siB = senders[e2]; riB = receivers[e2];
    }

    // 4) sigmoid in-register, pack, ONE b64 Ht write per mtile
#pragma unroll
    for (int mt = 0; mt < 5; ++mt) {
      uint p0 = cvt_pk(sigmoidf(acc[mt][0]), sigmoidf(acc[mt][1]));
      uint p1 = cvt_pk(sigmoidf(acc[mt][2]), sigmoidf(acc[mt][3]));
      *(uint2*)&Ht[pr][buf][c * HTS + wh * 80 + mt * 16 + g * 4] = make_uint2(p0, p1);
    }
    // raw barrier: LDS drained, but prefetch vmcnt stays in flight (no vmcnt(0))
    asm volatile("s_waitcnt lgkmcnt(0)\n\ts_barrier" ::: "memory");

    // 5) layer 2: A = h from Ht (b128, conflict-free stride), B = W2 regs
    f32x4 o = (f32x4){0.f, 0.f, 0.f, 0.f};
#pragma unroll
    for (int kt = 0; kt < 5; ++kt) {
      short8 af = *(const short8*)&Ht[pr][buf][c * HTS + kt * 32 + g * 8];
      o = __builtin_amdgcn_mfma_f32_16x16x32_bf16(af, w2f[kt], o, 0, 0, 0);
    }

    // 6) coalesced store: D[edge][dout], row = 4g+r, col = wh*16+c
    float* dst = out + (size_t)pt * 512 + (size_t)(g * 4) * 32 + wh * 16 + c;
#pragma unroll
    for (int r = 0; r < 4; ++r) dst[r * 32] = o[r] + b2r;

    pt += PSTRIDE;
    ptB = pt + PSTRIDE; if (ptB >= NPT) ptB = pt;
    eB  = (int)ptB * 16 + c;
    buf ^= 1;
  }
}

extern "C" void kernel_launch(void* const* d_in, const int* in_sizes, int n_in,
                              void* d_out, int out_size, void* d_ws, size_t ws_size,
                              hipStream_t stream) {
  const float* nodes     = (const float*)d_in[0];
  const float* edges     = (const float*)d_in[1];
  const int*   senders   = (const int*)d_in[2];
  const int*   receivers = (const int*)d_in[3];
  const float* W1        = (const float*)d_in[4];
  const float* b1        = (const float*)d_in[5];
  const float* W2        = (const float*)d_in[6];
  const float* b2        = (const float*)d_in[7];
  float* out = (float*)d_out;

  edge_mlp<<<GRID, 256, 0, stream>>>(nodes, edges, senders, receivers,
                                     W1, b1, W2, b2, out);
}

// Round 4
// 192.025 us; speedup vs baseline: 1.3923x; 1.3242x over previous
//
#include <hip/hip_runtime.h>

#define NEDGE  1600000
#define NPT    (NEDGE / 16)   // 100000 16-edge tiles
#define GRID   2500           // one wave-pair per block
#define NIT    (NPT / GRID)   // 40 — exact, no tail
#define WS_BYTES 40960        // 40 frags * 64 lanes * 16B

typedef float f32x4  __attribute__((ext_vector_type(4)));
typedef short short8 __attribute__((ext_vector_type(8)));

static __device__ __forceinline__ ushort f2bf(float f) {
  uint u = __builtin_bit_cast(uint, f);
  return (ushort)((u + 0x7FFFu + ((u >> 16) & 1u)) >> 16);   // RNE
}
static __device__ __forceinline__ uint cvt_pk(float lo, float hi) {
  uint r; asm("v_cvt_pk_bf16_f32 %0, %1, %2" : "=v"(r) : "v"(lo), "v"(hi)); return r;
}
static __device__ __forceinline__ float vexp2(float x) {
  float r; asm("v_exp_f32 %0, %1" : "=v"(r) : "v"(x)); return r;
}
static __device__ __forceinline__ float vrcp(float x) {
  float r; asm("v_rcp_f32 %0, %1" : "=v"(r) : "v"(x)); return r;
}
static __device__ __forceinline__ short8 pack8(float4 a, float4 b) {
  uint4 u;
  u.x = cvt_pk(a.x, a.y); u.y = cvt_pk(a.z, a.w);
  u.z = cvt_pk(b.x, b.y); u.w = cvt_pk(b.z, b.w);
  return __builtin_bit_cast(short8, u);
}

// Pre-pack W1 (scaled by -log2e, bias row at k=80, zeros to k=96, hid-permuted)
// and W2 (logical hid order) into MFMA fragment layout. 20480 bf16 elements.
__global__ void prep_frags(const float* __restrict__ W1, const float* __restrict__ b1,
                           const float* __restrict__ W2, ushort* __restrict__ ws) {
  const int idx = blockIdx.x * 256 + threadIdx.x;
  if (idx >= 20480) return;
  const int frag = idx >> 9;          // 512 elems per frag
  const int lane = (idx >> 3) & 63;
  const int j    = idx & 7;
  const int g = lane >> 4, c = lane & 15;
  ushort v;
  if (frag < 30) {                    // W1^T A-frags: frag = wh*15 + mt*3 + kt
    const int wh = frag / 15, rem = frag % 15, mt = rem / 3, kt = rem % 3;
    const int k   = kt * 32 + g * 8 + j;
    const int hid = 32 * mt + 8 * (c >> 2) + 4 * wh + (c & 3);   // permutation P
    const float s = -1.44269504088896f;
    const float val = (k < 80) ? W1[k * 160 + hid] * s
                               : (k == 80 ? b1[hid] * s : 0.0f);
    v = f2bf(val);
  } else {                            // W2^T A-frags: frag-30 = wh*5 + kt
    const int f2 = frag - 30, wh = f2 / 5, kt = f2 % 5;
    const int k = kt * 32 + g * 8 + j;
    v = f2bf(W2[k * 32 + 16 * wh + c]);
  }
  ws[idx] = v;
}

template <bool USE_WS>
__global__ __launch_bounds__(128) void edge_mlp(
    const float* __restrict__ nodes, const float* __restrict__ edges,
    const int* __restrict__ senders, const int* __restrict__ receivers,
    const float* __restrict__ W1, const float* __restrict__ b1,
    const float* __restrict__ W2, const float* __restrict__ b2,
    float* __restrict__ out, const ushort* __restrict__ ws)
{
  __shared__ uint2 X[2][2][5][64];   // [wave][dbuf][kt][lane] h-half exchange, 10 KB

  const int lane = threadIdx.x & 63;
  const int wh   = threadIdx.x >> 6;   // which wave of the pair
  const int g    = lane >> 4;          // 0..3
  const int c    = lane & 15;

  // ---- weight fragments in registers ----
  short8 w1f[5][3];   // L1 A-frags (W1^T, permuted, scaled, bias@k=80)
  short8 w2f[5];      // L2 A-frags (W2^T, this wave's 16-dout rows)
  if constexpr (USE_WS) {
#pragma unroll
    for (int mt = 0; mt < 5; ++mt)
#pragma unroll
      for (int kt = 0; kt < 3; ++kt)
        w1f[mt][kt] = *(const short8*)(ws + ((wh * 15 + mt * 3 + kt) * 64 + lane) * 8);
#pragma unroll
    for (int kt = 0; kt < 5; ++kt)
      w2f[kt] = *(const short8*)(ws + ((30 + wh * 5 + kt) * 64 + lane) * 8);
  } else {
    const float s = -1.44269504088896f;
    const int hidb = 8 * (c >> 2) + 4 * wh + (c & 3);
#pragma unroll
    for (int mt = 0; mt < 5; ++mt)
#pragma unroll
      for (int kt = 0; kt < 3; ++kt) {
        const int hid = 32 * mt + hidb;
        uint d[4];
#pragma unroll
        for (int dw = 0; dw < 4; ++dw) {
          const int k0 = kt * 32 + g * 8 + dw * 2, k1 = k0 + 1;
          const float f0 = (k0 < 80) ? W1[k0 * 160 + hid] * s : (k0 == 80 ? b1[hid] * s : 0.f);
          const float f1 = (k1 < 80) ? W1[k1 * 160 + hid] * s : (k1 == 80 ? b1[hid] * s : 0.f);
          d[dw] = (uint)f2bf(f0) | ((uint)f2bf(f1) << 16);
        }
        w1f[mt][kt] = __builtin_bit_cast(short8, make_uint4(d[0], d[1], d[2], d[3]));
      }
#pragma unroll
    for (int kt = 0; kt < 5; ++kt) {
      uint d[4];
#pragma unroll
      for (int dw = 0; dw < 4; ++dw) {
        const int k = kt * 32 + g * 8 + dw * 2;
        d[dw] = (uint)f2bf(W2[k * 32 + wh * 16 + c]) |
                ((uint)f2bf(W2[(k + 1) * 32 + wh * 16 + c]) << 16);
      }
      w2f[kt] = __builtin_bit_cast(short8, make_uint4(d[0], d[1], d[2], d[3]));
    }
  }
  const float4 b2v = *(const float4*)(b2 + wh * 16 + g * 4);   // rides acc init
  const uint   cE0 = (g == 2) ? 0x3F80u : 0u;                  // bf16(1.0) at k=80

  // ---- prologue: tile 0 gather + tile 1 indices ----
  int t = blockIdx.x;
  int e = t * 16 + c;
  float4 sn0, sn1, rn0, rn1, ee0, ee1;
  {
    const int si = senders[e], ri = receivers[e];
    const float* sp = nodes + (size_t)si * 32 + g * 8;
    sn0 = *(const float4*)sp;  sn1 = *(const float4*)(sp + 4);
    const float* rp = nodes + (size_t)ri * 32 + g * 8;
    rn0 = *(const float4*)rp;  rn1 = *(const float4*)(rp + 4);
    const float* ep = edges + (size_t)e * 16 + (g & 1) * 8;
    ee0 = *(const float4*)ep;  ee1 = *(const float4*)(ep + 4);
  }
  int e1 = (t + GRID) * 16 + c;          // tile 1 indices (always valid: t+GRID < NPT)
  int si1 = senders[e1], ri1 = receivers[e1];

  for (int i = 0; i < NIT; ++i) {
    const int buf = i & 1;

    // 1) pack current feats -> B-frags (waits in-flight gather)
    const short8 bfS = pack8(sn0, sn1);
    const short8 bfR = pack8(rn0, rn1);
    uint4 ue;
    ue.x = (g < 2) ? cvt_pk(ee0.x, ee0.y) : cE0;
    ue.y = (g < 2) ? cvt_pk(ee0.z, ee0.w) : 0u;
    ue.z = (g < 2) ? cvt_pk(ee1.x, ee1.y) : 0u;
    ue.w = (g < 2) ? cvt_pk(ee1.z, ee1.w) : 0u;
    const short8 bfE = __builtin_bit_cast(short8, ue);

    // 2) L1 swapped: acc[mt] = (W1^T)(mt) x feats^T  (5 independent chains)
    f32x4 acc[5];
#pragma unroll
    for (int mt = 0; mt < 5; ++mt) acc[mt] = (f32x4){0.f, 0.f, 0.f, 0.f};
#pragma unroll
    for (int mt = 0; mt < 5; ++mt)
      acc[mt] = __builtin_amdgcn_mfma_f32_16x16x32_bf16(w1f[mt][0], bfS, acc[mt], 0, 0, 0);
#pragma unroll
    for (int mt = 0; mt < 5; ++mt)
      acc[mt] = __builtin_amdgcn_mfma_f32_16x16x32_bf16(w1f[mt][1], bfR, acc[mt], 0, 0, 0);
#pragma unroll
    for (int mt = 0; mt < 5; ++mt)
      acc[mt] = __builtin_amdgcn_mfma_f32_16x16x32_bf16(w1f[mt][2], bfE, acc[mt], 0, 0, 0);

    // 3) prefetch tile i+1 gather (indices already in regs) + tile i+2 indices
    {
      int tn = t + GRID; if (tn >= NPT) tn = t;
      const int en = tn * 16 + c;
      const float* spn = nodes + (size_t)si1 * 32 + g * 8;
      sn0 = *(const float4*)spn;  sn1 = *(const float4*)(spn + 4);
      const float* rpn = nodes + (size_t)ri1 * 32 + g * 8;
      rn0 = *(const float4*)rpn;  rn1 = *(const float4*)(rpn + 4);
      const float* epn = edges + (size_t)en * 16 + (g & 1) * 8;
      ee0 = *(const float4*)epn;  ee1 = *(const float4*)(epn + 4);
      int t2 = t + 2 * GRID; if (t2 >= NPT) t2 = tn;
      const int e2 = t2 * 16 + c;
      si1 = senders[e2];  ri1 = receivers[e2];
    }

    // 4) sigmoid in-register (scale folded into W1/b1): h = rcp(1+exp2(x))
    uint pkA[5], pkB[5];
#pragma unroll
    for (int mt = 0; mt < 5; ++mt) {
      const float h0 = vrcp(1.0f + vexp2(acc[mt][0]));
      const float h1 = vrcp(1.0f + vexp2(acc[mt][1]));
      const float h2 = vrcp(1.0f + vexp2(acc[mt][2]));
      const float h3 = vrcp(1.0f + vexp2(acc[mt][3]));
      pkA[mt] = cvt_pk(h0, h1);
      pkB[mt] = cvt_pk(h2, h3);
    }

    // 5) lane-aligned half exchange with partner wave (permutation makes this exact)
#pragma unroll
    for (int kt = 0; kt < 5; ++kt) X[wh][buf][kt][lane] = make_uint2(pkA[kt], pkB[kt]);
    asm volatile("s_waitcnt lgkmcnt(0)\n\ts_barrier" ::: "memory");
    uint2 q[5];
#pragma unroll
    for (int kt = 0; kt < 5; ++kt) q[kt] = X[wh ^ 1][buf][kt][lane];

    // 6) L2 swapped: o = (W2^T rows) x h^T ; B-frag = [own pk | partner pk]
    f32x4 oa = (f32x4){b2v.x, b2v.y, b2v.z, b2v.w};   // b2 rides the init
    f32x4 ob = (f32x4){0.f, 0.f, 0.f, 0.f};
    if (wh == 0) {
#pragma unroll
      for (int kt = 0; kt < 5; ++kt) {
        const short8 bb = __builtin_bit_cast(short8,
            make_uint4(pkA[kt], pkB[kt], q[kt].x, q[kt].y));
        if (kt & 1) ob = __builtin_amdgcn_mfma_f32_16x16x32_bf16(w2f[kt], bb, ob, 0, 0, 0);
        else        oa = __builtin_amdgcn_mfma_f32_16x16x32_bf16(w2f[kt], bb, oa, 0, 0, 0);
      }
    } else {
#pragma unroll
      for (int kt = 0; kt < 5; ++kt) {
        const short8 bb = __builtin_bit_cast(short8,
            make_uint4(q[kt].x, q[kt].y, pkA[kt], pkB[kt]));
        if (kt & 1) ob = __builtin_amdgcn_mfma_f32_16x16x32_bf16(w2f[kt], bb, ob, 0, 0, 0);
        else        oa = __builtin_amdgcn_mfma_f32_16x16x32_bf16(w2f[kt], bb, oa, 0, 0, 0);
      }
    }
    const f32x4 o = oa + ob;

    // 7) store: lane covers dout [wh*16+4g, +4) of edge row c — full 64B sectors
    float4 st; st.x = o[0]; st.y = o[1]; st.z = o[2]; st.w = o[3];
    *(float4*)(out + (size_t)e * 32 + wh * 16 + g * 4) = st;

    t += GRID;
    e = t * 16 + c;
  }
}

extern "C" void kernel_launch(void* const* d_in, const int* in_sizes, int n_in,
                              void* d_out, int out_size, void* d_ws, size_t ws_size,
                              hipStream_t stream) {
  const float* nodes     = (const float*)d_in[0];
  const float* edges     = (const float*)d_in[1];
  const int*   senders   = (const int*)d_in[2];
  const int*   receivers = (const int*)d_in[3];
  const float* W1        = (const float*)d_in[4];
  const float* b1        = (const float*)d_in[5];
  const float* W2        = (const float*)d_in[6];
  const float* b2        = (const float*)d_in[7];
  float* out = (float*)d_out;

  if (ws_size >= WS_BYTES) {
    ushort* ws = (ushort*)d_ws;
    prep_frags<<<80, 256, 0, stream>>>(W1, b1, W2, ws);
    edge_mlp<true><<<GRID, 128, 0, stream>>>(nodes, edges, senders, receivers,
                                             W1, b1, W2, b2, out, ws);
  } else {
    edge_mlp<false><<<GRID, 128, 0, stream>>>(nodes, edges, senders, receivers,
                                              W1, b1, W2, b2, out, nullptr);
  }
}

// Round 5
// 157.488 us; speedup vs baseline: 1.6976x; 1.2193x over previous
//
#include <hip/hip_runtime.h>

#define NEDGE  1600000
#define NPT    (NEDGE / 16)   // 100000 16-edge tiles
#define GRID   2500           // one wave-pair per block
#define NIT    (NPT / GRID)   // 40 — exact, no tail
#define NNODE  100000
#define NB_OFF 32768                       // ushort offset of bf16 node cache in ws (byte 65536)
#define WS_BYTES (65536 + NNODE * 32 * 2)  // frags + bf16 nodes = 6,465,536

typedef float f32x4  __attribute__((ext_vector_type(4)));
typedef short short8 __attribute__((ext_vector_type(8)));

static __device__ __forceinline__ ushort f2bf(float f) {
  uint u = __builtin_bit_cast(uint, f);
  return (ushort)((u + 0x7FFFu + ((u >> 16) & 1u)) >> 16);   // RNE
}
static __device__ __forceinline__ uint cvt_pk(float lo, float hi) {
  uint r; asm("v_cvt_pk_bf16_f32 %0, %1, %2" : "=v"(r) : "v"(lo), "v"(hi)); return r;
}
static __device__ __forceinline__ float vexp2(float x) {
  float r; asm("v_exp_f32 %0, %1" : "=v"(r) : "v"(x)); return r;
}
static __device__ __forceinline__ float vrcp(float x) {
  float r; asm("v_rcp_f32 %0, %1" : "=v"(r) : "v"(x)); return r;
}
static __device__ __forceinline__ short8 pack8(float4 a, float4 b) {
  uint4 u;
  u.x = cvt_pk(a.x, a.y); u.y = cvt_pk(a.z, a.w);
  u.z = cvt_pk(b.x, b.y); u.w = cvt_pk(b.z, b.w);
  return __builtin_bit_cast(short8, u);
}

// Pre-pack W1 (scaled by -log2e, bias row at k=80, zeros to k=96, hid-permuted)
// and W2 into MFMA fragment layout. 20480 bf16 elements.
__global__ void prep_frags(const float* __restrict__ W1, const float* __restrict__ b1,
                           const float* __restrict__ W2, ushort* __restrict__ ws) {
  const int idx = blockIdx.x * 256 + threadIdx.x;
  if (idx >= 20480) return;
  const int frag = idx >> 9;
  const int lane = (idx >> 3) & 63;
  const int j    = idx & 7;
  const int g = lane >> 4, c = lane & 15;
  ushort v;
  if (frag < 30) {                    // W1^T A-frags: frag = wh*15 + mt*3 + kt
    const int wh = frag / 15, rem = frag % 15, mt = rem / 3, kt = rem % 3;
    const int k   = kt * 32 + g * 8 + j;
    const int hid = 32 * mt + 8 * (c >> 2) + 4 * wh + (c & 3);   // permutation P
    const float s = -1.44269504088896f;
    const float val = (k < 80) ? W1[k * 160 + hid] * s
                               : (k == 80 ? b1[hid] * s : 0.0f);
    v = f2bf(val);
  } else {                            // W2^T A-frags: frag-30 = wh*5 + kt
    const int f2 = frag - 30, wh = f2 / 5, kt = f2 % 5;
    const int k = kt * 32 + g * 8 + j;
    v = f2bf(W2[k * 32 + 16 * wh + c]);
  }
  ws[idx] = v;
}

// nodes f32 -> bf16 cache (row = 32 bf16 = 64B)
__global__ void prep_nodes(const float* __restrict__ nodes, ushort* __restrict__ nb) {
  const int idx = blockIdx.x * 256 + threadIdx.x;   // one per 8 floats
  if (idx >= NNODE * 4) return;
  const float4 a = ((const float4*)nodes)[idx * 2];
  const float4 b = ((const float4*)nodes)[idx * 2 + 1];
  *(short8*)(nb + (size_t)idx * 8) = pack8(a, b);
}

template <bool USE_WS>
__global__ __launch_bounds__(128) void edge_mlp(
    const float* __restrict__ nodes, const float* __restrict__ edges,
    const int* __restrict__ senders, const int* __restrict__ receivers,
    const float* __restrict__ W1, const float* __restrict__ b1,
    const float* __restrict__ W2, const float* __restrict__ b2,
    float* __restrict__ out, const ushort* __restrict__ ws)
{
  __shared__ uint2 X[2][2][5][64];   // [wave][dbuf][kt][lane] h-half exchange, 10 KB

  const int lane = threadIdx.x & 63;
  const int wh   = threadIdx.x >> 6;
  const int g    = lane >> 4;
  const int c    = lane & 15;
  const ushort* nb = USE_WS ? (ws + NB_OFF) : nullptr;

  // ---- weight fragments in registers ----
  short8 w1f[5][3];
  short8 w2f[5];
  if constexpr (USE_WS) {
#pragma unroll
    for (int mt = 0; mt < 5; ++mt)
#pragma unroll
      for (int kt = 0; kt < 3; ++kt)
        w1f[mt][kt] = *(const short8*)(ws + ((wh * 15 + mt * 3 + kt) * 64 + lane) * 8);
#pragma unroll
    for (int kt = 0; kt < 5; ++kt)
      w2f[kt] = *(const short8*)(ws + ((30 + wh * 5 + kt) * 64 + lane) * 8);
  } else {
    const float s = -1.44269504088896f;
    const int hidb = 8 * (c >> 2) + 4 * wh + (c & 3);
#pragma unroll
    for (int mt = 0; mt < 5; ++mt)
#pragma unroll
      for (int kt = 0; kt < 3; ++kt) {
        const int hid = 32 * mt + hidb;
        uint d[4];
#pragma unroll
        for (int dw = 0; dw < 4; ++dw) {
          const int k0 = kt * 32 + g * 8 + dw * 2, k1 = k0 + 1;
          const float f0 = (k0 < 80) ? W1[k0 * 160 + hid] * s : (k0 == 80 ? b1[hid] * s : 0.f);
          const float f1 = (k1 < 80) ? W1[k1 * 160 + hid] * s : (k1 == 80 ? b1[hid] * s : 0.f);
          d[dw] = (uint)f2bf(f0) | ((uint)f2bf(f1) << 16);
        }
        w1f[mt][kt] = __builtin_bit_cast(short8, make_uint4(d[0], d[1], d[2], d[3]));
      }
#pragma unroll
    for (int kt = 0; kt < 5; ++kt) {
      uint d[4];
#pragma unroll
      for (int dw = 0; dw < 4; ++dw) {
        const int k = kt * 32 + g * 8 + dw * 2;
        d[dw] = (uint)f2bf(W2[k * 32 + wh * 16 + c]) |
                ((uint)f2bf(W2[(k + 1) * 32 + wh * 16 + c]) << 16);
      }
      w2f[kt] = __builtin_bit_cast(short8, make_uint4(d[0], d[1], d[2], d[3]));
    }
  }
  const float4 b2v = *(const float4*)(b2 + wh * 16 + g * 4);
  const uint   cE0 = (g == 2) ? 0x3F80u : 0u;   // bf16(1.0) at k==80

  // ---- prologue: tile 0 gather + tile 1 indices ----
  int t = blockIdx.x;
  int e = t * 16 + c;
  short8 bfS_p, bfR_p;                 // USE_WS path: direct bf16 node frags
  float4 sn0, sn1, rn0, rn1;           // fallback path: f32 node rows
  float4 ee0, ee1;
  {
    const int si = senders[e], ri = receivers[e];
    if constexpr (USE_WS) {
      bfS_p = *(const short8*)(nb + (size_t)si * 32 + g * 8);
      bfR_p = *(const short8*)(nb + (size_t)ri * 32 + g * 8);
    } else {
      const float* sp = nodes + (size_t)si * 32 + g * 8;
      sn0 = *(const float4*)sp;  sn1 = *(const float4*)(sp + 4);
      const float* rp = nodes + (size_t)ri * 32 + g * 8;
      rn0 = *(const float4*)rp;  rn1 = *(const float4*)(rp + 4);
    }
    const float* ep = edges + (size_t)e * 16 + (g & 1) * 8;
    ee0 = *(const float4*)ep;  ee1 = *(const float4*)(ep + 4);
  }
  int e1 = (t + GRID) * 16 + c;
  int si1 = senders[e1], ri1 = receivers[e1];

  for (int i = 0; i < NIT; ++i) {
    const int buf = i & 1;

    // 1) edge feats -> bf16 frag (nodes need no pack on the USE_WS path)
    uint4 ue;
    ue.x = (g < 2) ? cvt_pk(ee0.x, ee0.y) : cE0;
    ue.y = (g < 2) ? cvt_pk(ee0.z, ee0.w) : 0u;
    ue.z = (g < 2) ? cvt_pk(ee1.x, ee1.y) : 0u;
    ue.w = (g < 2) ? cvt_pk(ee1.z, ee1.w) : 0u;
    const short8 bfE = __builtin_bit_cast(short8, ue);
    short8 bfS, bfR;
    if constexpr (USE_WS) { bfS = bfS_p;            bfR = bfR_p; }
    else                  { bfS = pack8(sn0, sn1);  bfR = pack8(rn0, rn1); }

    // 2) L1 swapped: acc[mt] = (W1^T)(mt) x feats^T
    f32x4 acc[5];
#pragma unroll
    for (int mt = 0; mt < 5; ++mt) acc[mt] = (f32x4){0.f, 0.f, 0.f, 0.f};
#pragma unroll
    for (int mt = 0; mt < 5; ++mt)
      acc[mt] = __builtin_amdgcn_mfma_f32_16x16x32_bf16(w1f[mt][0], bfS, acc[mt], 0, 0, 0);
#pragma unroll
    for (int mt = 0; mt < 5; ++mt)
      acc[mt] = __builtin_amdgcn_mfma_f32_16x16x32_bf16(w1f[mt][1], bfR, acc[mt], 0, 0, 0);
#pragma unroll
    for (int mt = 0; mt < 5; ++mt)
      acc[mt] = __builtin_amdgcn_mfma_f32_16x16x32_bf16(w1f[mt][2], bfE, acc[mt], 0, 0, 0);

    // 3) prefetch next tile (edges first, then nodes, then indices 2-ahead)
    {
      int tn = t + GRID; if (tn >= NPT) tn = t;
      const int en = tn * 16 + c;
      const float* epn = edges + (size_t)en * 16 + (g & 1) * 8;
      ee0 = *(const float4*)epn;  ee1 = *(const float4*)(epn + 4);
      if constexpr (USE_WS) {
        bfS_p = *(const short8*)(nb + (size_t)si1 * 32 + g * 8);
        bfR_p = *(const short8*)(nb + (size_t)ri1 * 32 + g * 8);
      } else {
        const float* spn = nodes + (size_t)si1 * 32 + g * 8;
        sn0 = *(const float4*)spn;  sn1 = *(const float4*)(spn + 4);
        const float* rpn = nodes + (size_t)ri1 * 32 + g * 8;
        rn0 = *(const float4*)rpn;  rn1 = *(const float4*)(rpn + 4);
      }
      int t2 = t + 2 * GRID; if (t2 >= NPT) t2 = tn;
      const int e2 = t2 * 16 + c;
      si1 = senders[e2];  ri1 = receivers[e2];
    }

    // 4) sigmoid in-register (scale folded into W1/b1): h = rcp(1+exp2(x))
    uint pkA[5], pkB[5];
#pragma unroll
    for (int mt = 0; mt < 5; ++mt) {
      const float h0 = vrcp(1.0f + vexp2(acc[mt][0]));
      const float h1 = vrcp(1.0f + vexp2(acc[mt][1]));
      const float h2 = vrcp(1.0f + vexp2(acc[mt][2]));
      const float h3 = vrcp(1.0f + vexp2(acc[mt][3]));
      pkA[mt] = cvt_pk(h0, h1);
      pkB[mt] = cvt_pk(h2, h3);
    }

    // 5) lane-aligned half exchange with partner wave
#pragma unroll
    for (int kt = 0; kt < 5; ++kt) X[wh][buf][kt][lane] = make_uint2(pkA[kt], pkB[kt]);
    asm volatile("s_waitcnt lgkmcnt(0)\n\ts_barrier" ::: "memory");
    uint2 q[5];
#pragma unroll
    for (int kt = 0; kt < 5; ++kt) q[kt] = X[wh ^ 1][buf][kt][lane];

    // 6) L2 swapped: o = (W2^T rows) x h^T ; B-frag = [own pk | partner pk]
    f32x4 oa = (f32x4){b2v.x, b2v.y, b2v.z, b2v.w};
    f32x4 ob = (f32x4){0.f, 0.f, 0.f, 0.f};
    if (wh == 0) {
#pragma unroll
      for (int kt = 0; kt < 5; ++kt) {
        const short8 bb = __builtin_bit_cast(short8,
            make_uint4(pkA[kt], pkB[kt], q[kt].x, q[kt].y));
        if (kt & 1) ob = __builtin_amdgcn_mfma_f32_16x16x32_bf16(w2f[kt], bb, ob, 0, 0, 0);
        else        oa = __builtin_amdgcn_mfma_f32_16x16x32_bf16(w2f[kt], bb, oa, 0, 0, 0);
      }
    } else {
#pragma unroll
      for (int kt = 0; kt < 5; ++kt) {
        const short8 bb = __builtin_bit_cast(short8,
            make_uint4(q[kt].x, q[kt].y, pkA[kt], pkB[kt]));
        if (kt & 1) ob = __builtin_amdgcn_mfma_f32_16x16x32_bf16(w2f[kt], bb, ob, 0, 0, 0);
        else        oa = __builtin_amdgcn_mfma_f32_16x16x32_bf16(w2f[kt], bb, oa, 0, 0, 0);
      }
    }
    const f32x4 o = oa + ob;

    // 7) coalesced store
    float4 st; st.x = o[0]; st.y = o[1]; st.z = o[2]; st.w = o[3];
    *(float4*)(out + (size_t)e * 32 + wh * 16 + g * 4) = st;

    t += GRID;
    e = t * 16 + c;
  }
}

extern "C" void kernel_launch(void* const* d_in, const int* in_sizes, int n_in,
                              void* d_out, int out_size, void* d_ws, size_t ws_size,
                              hipStream_t stream) {
  const float* nodes     = (const float*)d_in[0];
  const float* edges     = (const float*)d_in[1];
  const int*   senders   = (const int*)d_in[2];
  const int*   receivers = (const int*)d_in[3];
  const float* W1        = (const float*)d_in[4];
  const float* b1        = (const float*)d_in[5];
  const float* W2        = (const float*)d_in[6];
  const float* b2        = (const float*)d_in[7];
  float* out = (float*)d_out;

  if (ws_size >= (size_t)WS_BYTES) {
    ushort* ws = (ushort*)d_ws;
    prep_frags<<<80, 256, 0, stream>>>(W1, b1, W2, ws);
    prep_nodes<<<(NNODE * 4 + 255) / 256, 256, 0, stream>>>(nodes, ws + NB_OFF);
    edge_mlp<true><<<GRID, 128, 0, stream>>>(nodes, edges, senders, receivers,
                                             W1, b1, W2, b2, out, ws);
  } else {
    edge_mlp<false><<<GRID, 128, 0, stream>>>(nodes, edges, senders, receivers,
                                              W1, b1, W2, b2, out, nullptr);
  }
}